// Round 14
// baseline (8774.339 us; speedup 1.0000x reference)
//
#include <hip/hip_runtime.h>

typedef unsigned short u16;
typedef unsigned int u32;
typedef unsigned long long u64;
typedef __attribute__((ext_vector_type(4))) float f32x4;
typedef __attribute__((ext_vector_type(8))) short s16x8;

__device__ __forceinline__ float bf2f(u16 u) {
  union { u32 i; float f; } x;
  x.i = ((u32)u) << 16;
  return x.f;
}
__device__ __forceinline__ u16 f2bf(float f) {
  union { float f; u32 i; } u;
  u.f = f;
  u32 r = u.i + 0x7fffu + ((u.i >> 16) & 1u);
  return (u16)(r >> 16);
}

static inline int nblk6(long long n) { return (int)((n + 255) / 256); }

// identifier-named symbol; generic zero-fill
__global__ void HeteroGraphSAGE_52931176955955_kernel(float* p, long long n) {
  long long i = (long long)blockIdx.x * 256 + threadIdx.x;
  if (i < n) p[i] = 0.0f;
}

// ---------------- weight prep: 25 bf16 W^T mats (n-major) ----------------
// w<11: Wl[w]; 11..21: Wr[w-11]; 22: Wr2+Wr4; 23: Wr6+Wr8; 24: Wr7+Wr10
__global__ void g_wprep(const float* Wl, const float* Wr, u16* wt, int total) {
  int idx = blockIdx.x * 256 + threadIdx.x;
  if (idx >= total) return;
  int w = idx >> 14;
  int r = idx & 16383;
  int n = r >> 7, k = r & 127;
  float v;
  if (w < 11) v = Wl[w * 16384 + k * 128 + n];
  else if (w < 22) v = Wr[(w - 11) * 16384 + k * 128 + n];
  else {
    int a = (w == 22) ? 2 : (w == 23) ? 6 : 7;
    int b = (w == 22) ? 4 : (w == 23) ? 8 : 10;
    v = Wr[a * 16384 + k * 128 + n] + Wr[b * 16384 + k * 128 + n];
  }
  wt[idx] = f2bf(v);
}

// combined biases for the 3 dual sages
__global__ void g_bprep(const float* bL, float* cb) {
  int c = threadIdx.x;  // 128
  cb[c]       = bL[2 * 128 + c] + bL[4 * 128 + c];
  cb[128 + c] = bL[6 * 128 + c] + bL[8 * 128 + c];
  cb[256 + c] = bL[7 * 128 + c] + bL[10 * 128 + c];
}

// fp32 -> bf16, 4/thread
__global__ void g_cvt(const float* x, u16* o, long long n4) {
  long long i = (long long)blockIdx.x * 256 + threadIdx.x;
  if (i >= n4) return;
  f32x4 v = *(const f32x4*)(x + (i << 2));
  u64 p = ((u64)f2bf(v.x)) | (((u64)f2bf(v.y)) << 16) |
          (((u64)f2bf(v.z)) << 32) | (((u64)f2bf(v.w)) << 48);
  *(u64*)(o + (i << 2)) = p;
}

// ---------------- CSR build ----------------
__global__ void g_deg(const int* e, int E, int* deg) {
  int w = blockIdx.x * 256 + threadIdx.x;
  if (w >= E) return;
  atomicAdd(deg + e[E + w], 1);
}

__global__ void g_scan(const int* deg, int* rp, int n) {
  __shared__ int wsum[16];
  __shared__ int base;
  int tid = threadIdx.x;
  int lane = tid & 63;
  int wv = tid >> 6;
  if (tid == 0) { base = 0; rp[0] = 0; }
  __syncthreads();
  for (int start = 0; start < n; start += 1024) {
    int i = start + tid;
    int x = (i < n) ? deg[i] : 0;
    for (int ofs = 1; ofs < 64; ofs <<= 1) {
      int t = __shfl_up(x, ofs);
      if (lane >= ofs) x += t;
    }
    if (lane == 63) wsum[wv] = x;
    __syncthreads();
    if (wv == 0 && lane < 16) {
      int y = wsum[lane];
      for (int ofs = 1; ofs < 16; ofs <<= 1) {
        int t = __shfl_up(y, ofs);
        if (lane >= ofs) y += t;
      }
      wsum[lane] = y;
    }
    __syncthreads();
    int wbase = (wv > 0) ? wsum[wv - 1] : 0;
    if (i < n) rp[i + 1] = base + wbase + x;
    __syncthreads();
    if (tid == 0) base += wsum[15];
    __syncthreads();
  }
}

__global__ void g_fill(const int* e, int E, const int* rp, int* cur, int* col) {
  int w = blockIdx.x * 256 + threadIdx.x;
  if (w >= E) return;
  int s = e[w];
  int d = e[E + w];
  int pos = atomicAdd(cur + d, 1);
  col[rp[d] + pos] = s;
}

// ---------------- fused (dual-edge) gather + transform + MFMA SAGE ----------------
// out[r,:] = T_A-mean @ WlA (+ T_B-mean @ WlB) (+ T_R(root) @ Wr) + bias
// where T(v) = relu(v)*sc + sh if scsh given, else v. All srcs bf16 (root may be fp32).
// block = 256 thr (4 waves), 32 rows.
__device__ __forceinline__ void stage_store(u16* sm, int rr, int q, const float* acc) {
  s16x8 o;
#pragma unroll
  for (int e = 0; e < 8; ++e) o[e] = (short)f2bf(acc[e]);
  int byte = (rr << 8) + (q << 4);
  int swz = byte ^ ((rr & 7) << 4);
  *(s16x8*)((char*)sm + swz) = o;
}

__global__ __launch_bounds__(256) void g_sage(
    const int* rpA, const int* colA, const u16* srcA, const float* scshA, const u16* wtlA,
    const int* rpB, const int* colB, const u16* srcB, const float* scshB, const u16* wtlB,
    const void* root, int root_f32, const float* scshR, const u16* wtr,
    const float* bias, void* out, int out_bf, int N) {
  __shared__ __align__(16) u16 smA[4096];
  __shared__ __align__(16) u16 smB[4096];
  __shared__ __align__(16) u16 smR[4096];
  const int tid = threadIdx.x;
  const int r0 = blockIdx.x * 32;
  const int nbuf = 1 + (rpB ? 1 : 0) + (root ? 1 : 0);

  for (int i = tid; i < nbuf * 512; i += 256) {
    int region = i >> 9;
    int t = i & 511;
    int rr = t >> 4, q = t & 15;
    int row = r0 + rr;
    int c0 = q * 8;
    float acc[8];
#pragma unroll
    for (int e = 0; e < 8; ++e) acc[e] = 0.f;

    bool isRoot = root && (region == nbuf - 1);
    if (isRoot) {
      if (row < N) {
        if (root_f32) {
          const float* rp_ = (const float*)root + (size_t)row * 128 + c0;
          f32x4 lo = *(const f32x4*)rp_;
          f32x4 hi = *(const f32x4*)(rp_ + 4);
          acc[0] = lo.x; acc[1] = lo.y; acc[2] = lo.z; acc[3] = lo.w;
          acc[4] = hi.x; acc[5] = hi.y; acc[6] = hi.z; acc[7] = hi.w;
        } else {
          s16x8 v = *(const s16x8*)((const u16*)root + (size_t)row * 128 + c0);
#pragma unroll
          for (int e = 0; e < 8; ++e) acc[e] = bf2f((u16)v[e]);
        }
        if (scshR) {
#pragma unroll
          for (int e = 0; e < 8; ++e)
            acc[e] = fmaxf(acc[e], 0.f) * scshR[c0 + e] + scshR[128 + c0 + e];
        }
      }
      stage_store(smR, rr, q, acc);
    } else {
      const int* rp = (region == 0) ? rpA : rpB;
      const int* col = (region == 0) ? colA : colB;
      const u16* src = (region == 0) ? srcA : srcB;
      const float* scsh = (region == 0) ? scshA : scshB;
      if (row < N) {
        int j0 = rp[row], j1 = rp[row + 1];
        if (scsh) {
          float sc[8], sh[8];
#pragma unroll
          for (int e = 0; e < 8; ++e) { sc[e] = scsh[c0 + e]; sh[e] = scsh[128 + c0 + e]; }
          for (int j = j0; j < j1; ++j) {
            s16x8 v = *(const s16x8*)(src + (size_t)col[j] * 128 + c0);
#pragma unroll
            for (int e = 0; e < 8; ++e)
              acc[e] += fmaxf(bf2f((u16)v[e]), 0.f) * sc[e] + sh[e];
          }
        } else {
          for (int j = j0; j < j1; ++j) {
            s16x8 v = *(const s16x8*)(src + (size_t)col[j] * 128 + c0);
#pragma unroll
            for (int e = 0; e < 8; ++e) acc[e] += bf2f((u16)v[e]);
          }
        }
        float inv = 1.0f / fmaxf((float)(j1 - j0), 1.0f);
#pragma unroll
        for (int e = 0; e < 8; ++e) acc[e] *= inv;
      }
      stage_store((region == 0) ? smA : smB, rr, q, acc);
    }
  }
  __syncthreads();

  // ---- MFMA: wave wv -> row-tile m=wv>>1, col-tiles nq..nq+3 ----
  const int lane = tid & 63;
  const int wv = tid >> 6;
  const int mi = lane & 15;
  const int kg = lane >> 4;
  const int m = wv >> 1;
  const int nq = (wv & 1) * 4;
  const int arow = m * 16 + mi;
  const int abase = arow << 8;
  const int amask = (arow & 7) << 4;

  f32x4 acc4[4];
#pragma unroll
  for (int t = 0; t < 4; ++t) acc4[t] = (f32x4){0.f, 0.f, 0.f, 0.f};

#pragma unroll
  for (int kt = 0; kt < 4; ++kt) {
    int k0 = kt * 32 + kg * 8;
    int off = (abase + (k0 << 1)) ^ amask;
    s16x8 afA = *(const s16x8*)((const char*)smA + off);
    s16x8 afB, afR;
    if (rpB) afB = *(const s16x8*)((const char*)smB + off);
    if (root) afR = *(const s16x8*)((const char*)smR + off);
#pragma unroll
    for (int t = 0; t < 4; ++t) {
      int cr = (nq + t) * 16 + mi;
      s16x8 b = *(const s16x8*)(wtlA + cr * 128 + k0);
      acc4[t] = __builtin_amdgcn_mfma_f32_16x16x32_bf16(afA, b, acc4[t], 0, 0, 0);
      if (rpB) {
        s16x8 b2 = *(const s16x8*)(wtlB + cr * 128 + k0);
        acc4[t] = __builtin_amdgcn_mfma_f32_16x16x32_bf16(afB, b2, acc4[t], 0, 0, 0);
      }
      if (root) {
        s16x8 b3 = *(const s16x8*)(wtr + cr * 128 + k0);
        acc4[t] = __builtin_amdgcn_mfma_f32_16x16x32_bf16(afR, b3, acc4[t], 0, 0, 0);
      }
    }
  }

  // ---- epilogue: C/D col=lane&15, row=(lane>>4)*4+reg [m89] ----
  int rbase = (lane >> 4) << 2;
#pragma unroll
  for (int t = 0; t < 4; ++t) {
    int c = (nq + t) * 16 + mi;
    float bb = bias[c];
#pragma unroll
    for (int reg = 0; reg < 4; ++reg) {
      int row = r0 + m * 16 + rbase + reg;
      if (row < N) {
        size_t o = (size_t)row * 128 + c;
        float v = acc4[t][reg] + bb;
        if (out_bf) ((u16*)out)[o] = f2bf(v);
        else        ((float*)out)[o] = v;
      }
    }
  }
}

// ---------------- BN stats over relu(raw bf16), 4 elems/thread ----------------
__global__ void g_bnstats(const u16* x, long long n4, float* stats) {
  long long i0 = (long long)blockIdx.x * 256 + threadIdx.x;
  long long stride = (long long)gridDim.x * 256;
  int c0 = (int)((i0 << 2) & 127);
  float s0 = 0.f, s1 = 0.f, s2 = 0.f, s3 = 0.f;
  float q0 = 0.f, q1 = 0.f, q2 = 0.f, q3 = 0.f;
  for (long long i = i0; i < n4; i += stride) {
    u64 v = *(const u64*)(x + (i << 2));
    float f0 = fmaxf(bf2f((u16)v), 0.f);
    float f1 = fmaxf(bf2f((u16)(v >> 16)), 0.f);
    float f2 = fmaxf(bf2f((u16)(v >> 32)), 0.f);
    float f3 = fmaxf(bf2f((u16)(v >> 48)), 0.f);
    s0 += f0; s1 += f1; s2 += f2; s3 += f3;
    q0 += f0 * f0; q1 += f1 * f1; q2 += f2 * f2; q3 += f3 * f3;
  }
  atomicAdd(stats + c0,     s0); atomicAdd(stats + c0 + 1, s1);
  atomicAdd(stats + c0 + 2, s2); atomicAdd(stats + c0 + 3, s3);
  atomicAdd(stats + 128 + c0,     q0); atomicAdd(stats + 128 + c0 + 1, q1);
  atomicAdd(stats + 128 + c0 + 2, q2); atomicAdd(stats + 128 + c0 + 3, q3);
}

__global__ void g_bnfin(const float* stats, const float* g, const float* b,
                        float invN, float* scsh) {
  int c = threadIdx.x;  // 128
  float m = stats[c] * invN;
  float v = stats[128 + c] * invN - m * m;
  float sc = rsqrtf(v + 1e-5f) * g[c];
  scsh[c] = sc;
  scsh[128 + c] = b[c] - m * sc;
}

// ---------------- host ----------------
struct Csr { int* rp; int* col; };

static void build_csr(const int* e, int E, int ndst, Csr c, int* cur, hipStream_t st) {
  HeteroGraphSAGE_52931176955955_kernel<<<nblk6(ndst), 256, 0, st>>>((float*)cur, ndst);
  g_deg<<<nblk6(E), 256, 0, st>>>(e, E, cur);
  g_scan<<<1, 1024, 0, st>>>(cur, c.rp, ndst);
  HeteroGraphSAGE_52931176955955_kernel<<<nblk6(ndst), 256, 0, st>>>((float*)cur, ndst);
  g_fill<<<nblk6(E), 256, 0, st>>>(e, E, c.rp, cur, c.col);
}

static void bn_v6(const u16* h, int n, const float* g, const float* b,
                  float* stats, float* scsh, hipStream_t st) {
  HeteroGraphSAGE_52931176955955_kernel<<<1, 256, 0, st>>>(stats, 256);
  g_bnstats<<<1024, 256, 0, st>>>(h, (long long)n * 32, stats);
  g_bnfin<<<1, 128, 0, st>>>(stats, g, b, 1.0f / (float)n, scsh);
}

extern "C" void kernel_launch(void* const* d_in, const int* in_sizes, int n_in,
                              void* d_out, int out_size, void* d_ws, size_t ws_size,
                              hipStream_t stream) {
  const float* x_paper  = (const float*)d_in[0];
  const float* x_author = (const float*)d_in[1];
  const int* e_pp = (const int*)d_in[3];
  const int* e_pa = (const int*)d_in[4];
  const int* e_ap = (const int*)d_in[5];
  const int* e_ai = (const int*)d_in[6];
  const int* e_ia = (const int*)d_in[7];
  const float* Wl  = (const float*)d_in[8];
  const float* bL  = (const float*)d_in[9];
  const float* Wr  = (const float*)d_in[10];
  const float* bng = (const float*)d_in[11];
  const float* bnb = (const float*)d_in[12];

  const int NP = in_sizes[0] / 128;
  const int NA = in_sizes[1] / 128;
  const int NI = in_sizes[2] / 128;
  const int Epp = in_sizes[3] / 2;
  const int Epa = in_sizes[4] / 2;
  const int Eap = in_sizes[5] / 2;
  const int Eai = in_sizes[6] / 2;
  const int Eia = in_sizes[7] / 2;

  // ws (~153 MB)
  char* ws = (char*)d_ws;
  size_t off = 0;
  u16* xp   = (u16*)(ws + off);   off += (size_t)NP * 256;   // x_paper bf16
  u16* h_p1 = (u16*)(ws + off);   off += (size_t)NP * 256;
  u16* h_a1 = (u16*)(ws + off);   off += (size_t)NA * 256;
  u16* wt   = (u16*)(ws + off);   off += (size_t)25 * 16384 * 2;
  Csr cpp; cpp.rp = (int*)(ws + off); off += (size_t)(NP + 1) * 4;
  Csr cpa; cpa.rp = (int*)(ws + off); off += (size_t)(NA + 1) * 4;
  Csr cap; cap.rp = (int*)(ws + off); off += (size_t)(NP + 1) * 4;
  Csr cai; cai.rp = (int*)(ws + off); off += (size_t)(NI + 1) * 4;
  Csr cia; cia.rp = (int*)(ws + off); off += (size_t)(NA + 1) * 4;
  cpp.col = (int*)(ws + off); off += (size_t)Epp * 4;
  cpa.col = (int*)(ws + off); off += (size_t)Epa * 4;
  cap.col = (int*)(ws + off); off += (size_t)Eap * 4;
  cai.col = (int*)(ws + off); off += (size_t)Eai * 4;
  cia.col = (int*)(ws + off); off += (size_t)Eia * 4;
  int* cur = (int*)(ws + off);       off += (size_t)NP * 4;
  float* stats = (float*)(ws + off); off += 1024;
  float* scsh0 = (float*)(ws + off); off += 1024;
  float* scsh1 = (float*)(ws + off); off += 1024;
  float* scsh2 = (float*)(ws + off); off += 1024;
  float* scsh3 = (float*)(ws + off); off += 1024;
  float* scsh4 = (float*)(ws + off); off += 1024;
  float* cb    = (float*)(ws + off); off += 3 * 512;

  // d_out fp32 regions: p2 | a2 | i2; raw bf16 hiddens parked inside
  float* outp = (float*)d_out;
  float* outa = outp + (size_t)NP * 128;
  float* outi = outa + (size_t)NA * 128;
  u16* h_p0 = (u16*)outp;                         // first half of p-region
  u16* h_a0 = (u16*)outa;                         // first half of a-region
  u16* h_i1 = (u16*)outp + (size_t)NP * 128;      // second half of p-region

  g_wprep<<<nblk6(25 * 16384), 256, 0, stream>>>(Wl, Wr, wt, 25 * 16384);
  g_bprep<<<1, 128, 0, stream>>>(bL, cb);
  g_cvt<<<nblk6((long long)NP * 32), 256, 0, stream>>>(x_paper, xp, (long long)NP * 32);
  build_csr(e_pp, Epp, NP, cpp, cur, stream);
  build_csr(e_pa, Epa, NA, cpa, cur, stream);
  build_csr(e_ap, Eap, NP, cap, cur, stream);
  build_csr(e_ai, Eai, NI, cai, cur, stream);
  build_csr(e_ia, Eia, NA, cia, cur, stream);

  const float* nof = (const float*)0;
  const int* noi = (const int*)0;
  const u16* nou = (const u16*)0;

#define WT(i) (wt + (size_t)(i) * 16384)

  // ---- Layer 0 (raw outputs; BN stats -> scsh) ----
  g_sage<<<(NP + 31) / 32, 256, 0, stream>>>(
      cpp.rp, cpp.col, xp, nof, WT(0), noi, noi, nou, nof, nou,
      xp, 0, nof, WT(11), bL + 0 * 128, h_p0, 1, NP);
  bn_v6(h_p0, NP, bng + 0 * 128, bnb + 0 * 128, stats, scsh0, stream);
  g_sage<<<(NA + 31) / 32, 256, 0, stream>>>(
      cpa.rp, cpa.col, xp, nof, WT(1), noi, noi, nou, nof, nou,
      x_author, 1, nof, WT(12), bL + 1 * 128, h_a0, 1, NA);
  bn_v6(h_a0, NA, bng + 1 * 128, bnb + 1 * 128, stats, scsh1, stream);

  // ---- Layer 1 ----
  g_sage<<<(NP + 31) / 32, 256, 0, stream>>>(             // p1 = pp + ap (dual)
      cpp.rp, cpp.col, h_p0, scsh0, WT(2), cap.rp, cap.col, h_a0, scsh1, WT(4),
      h_p0, 0, scsh0, WT(22), cb, h_p1, 1, NP);
  bn_v6(h_p1, NP, bng + 2 * 128, bnb + 2 * 128, stats, scsh2, stream);
  g_sage<<<(NA + 31) / 32, 256, 0, stream>>>(             // a1 = pa
      cpa.rp, cpa.col, h_p0, scsh0, WT(3), noi, noi, nou, nof, nou,
      h_a0, 0, scsh1, WT(14), bL + 3 * 128, h_a1, 1, NA);
  bn_v6(h_a1, NA, bng + 3 * 128, bnb + 3 * 128, stats, scsh3, stream);
  g_sage<<<(NI + 31) / 32, 256, 0, stream>>>(             // i1 = ai (no root)
      cai.rp, cai.col, h_a0, scsh1, WT(5), noi, noi, nou, nof, nou,
      (const void*)0, 0, nof, nou, bL + 5 * 128, h_i1, 1, NI);
  bn_v6(h_i1, NI, bng + 4 * 128, bnb + 4 * 128, stats, scsh4, stream);

  // ---- Layer 2 (order: a2, i2, then p2 — p2 clobbers h_i1's region) ----
  g_sage<<<(NA + 31) / 32, 256, 0, stream>>>(             // a2 = pa + ia (dual)
      cpa.rp, cpa.col, h_p1, scsh2, WT(7), cia.rp, cia.col, h_i1, scsh4, WT(10),
      h_a1, 0, scsh3, WT(24), cb + 256, outa, 0, NA);
  g_sage<<<(NI + 31) / 32, 256, 0, stream>>>(             // i2 = ai
      cai.rp, cai.col, h_a1, scsh3, WT(9), noi, noi, nou, nof, nou,
      h_i1, 0, scsh4, WT(20), bL + 9 * 128, outi, 0, NI);
  g_sage<<<(NP + 31) / 32, 256, 0, stream>>>(             // p2 = pp + ap (dual)
      cpp.rp, cpp.col, h_p1, scsh2, WT(6), cap.rp, cap.col, h_a1, scsh3, WT(8),
      h_p1, 0, scsh2, WT(23), cb + 128, outp, 0, NP);

#undef WT
  (void)n_in; (void)ws_size; (void)out_size;
}

// Round 15
// 2210.760 us; speedup vs baseline: 3.9689x; 3.9689x over previous
//
#include <hip/hip_runtime.h>

typedef unsigned short u16;
typedef unsigned int u32;
typedef unsigned long long u64;
typedef __attribute__((ext_vector_type(4))) float f32x4;
typedef __attribute__((ext_vector_type(8))) short s16x8;

__device__ __forceinline__ float bf2f(u16 u) {
  union { u32 i; float f; } x;
  x.i = ((u32)u) << 16;
  return x.f;
}
__device__ __forceinline__ u16 f2bf(float f) {
  union { float f; u32 i; } u;
  u.f = f;
  u32 r = u.i + 0x7fffu + ((u.i >> 16) & 1u);
  return (u16)(r >> 16);
}

static inline int nblk7(long long n) { return (int)((n + 255) / 256); }

// identifier-named symbol; generic zero-fill
__global__ void HeteroGraphSAGE_52931176955955_kernel(float* p, long long n) {
  long long i = (long long)blockIdx.x * 256 + threadIdx.x;
  if (i < n) p[i] = 0.0f;
}

// ---------------- weight prep: 25 bf16 W^T mats (n-major) ----------------
// w<11: Wl[w]; 11..21: Wr[w-11]; 22: Wr2+Wr4; 23: Wr6+Wr8; 24: Wr7+Wr10
__global__ void g_wprep(const float* Wl, const float* Wr, u16* wt, int total) {
  int idx = blockIdx.x * 256 + threadIdx.x;
  if (idx >= total) return;
  int w = idx >> 14;
  int r = idx & 16383;
  int n = r >> 7, k = r & 127;
  float v;
  if (w < 11) v = Wl[w * 16384 + k * 128 + n];
  else if (w < 22) v = Wr[(w - 11) * 16384 + k * 128 + n];
  else {
    int a = (w == 22) ? 2 : (w == 23) ? 6 : 7;
    int b = (w == 22) ? 4 : (w == 23) ? 8 : 10;
    v = Wr[a * 16384 + k * 128 + n] + Wr[b * 16384 + k * 128 + n];
  }
  wt[idx] = f2bf(v);
}

// combined biases for the 3 dual sages
__global__ void g_bprep(const float* bL, float* cb) {
  int c = threadIdx.x;  // 128
  cb[c]       = bL[2 * 128 + c] + bL[4 * 128 + c];
  cb[128 + c] = bL[6 * 128 + c] + bL[8 * 128 + c];
  cb[256 + c] = bL[7 * 128 + c] + bL[10 * 128 + c];
}

// fp32 -> bf16, 4/thread
__global__ void g_cvt(const float* x, u16* o, long long n4) {
  long long i = (long long)blockIdx.x * 256 + threadIdx.x;
  if (i >= n4) return;
  f32x4 v = *(const f32x4*)(x + (i << 2));
  u64 p = ((u64)f2bf(v.x)) | (((u64)f2bf(v.y)) << 16) |
          (((u64)f2bf(v.z)) << 32) | (((u64)f2bf(v.w)) << 48);
  *(u64*)(o + (i << 2)) = p;
}

// ---------------- CSR build ----------------
__global__ void g_deg(const int* e, int E, int* deg) {
  int w = blockIdx.x * 256 + threadIdx.x;
  if (w >= E) return;
  atomicAdd(deg + e[E + w], 1);
}

__global__ void g_scan(const int* deg, int* rp, int n) {
  __shared__ int wsum[16];
  __shared__ int base;
  int tid = threadIdx.x;
  int lane = tid & 63;
  int wv = tid >> 6;
  if (tid == 0) { base = 0; rp[0] = 0; }
  __syncthreads();
  for (int start = 0; start < n; start += 1024) {
    int i = start + tid;
    int x = (i < n) ? deg[i] : 0;
    for (int ofs = 1; ofs < 64; ofs <<= 1) {
      int t = __shfl_up(x, ofs);
      if (lane >= ofs) x += t;
    }
    if (lane == 63) wsum[wv] = x;
    __syncthreads();
    if (wv == 0 && lane < 16) {
      int y = wsum[lane];
      for (int ofs = 1; ofs < 16; ofs <<= 1) {
        int t = __shfl_up(y, ofs);
        if (lane >= ofs) y += t;
      }
      wsum[lane] = y;
    }
    __syncthreads();
    int wbase = (wv > 0) ? wsum[wv - 1] : 0;
    if (i < n) rp[i + 1] = base + wbase + x;
    __syncthreads();
    if (tid == 0) base += wsum[15];
    __syncthreads();
  }
}

__global__ void g_fill(const int* e, int E, const int* rp, int* cur, int* col) {
  int w = blockIdx.x * 256 + threadIdx.x;
  if (w >= E) return;
  int s = e[w];
  int d = e[E + w];
  int pos = atomicAdd(cur + d, 1);
  col[rp[d] + pos] = s;
}

// ---------------- fused (dual-edge) gather + transform + MFMA SAGE ----------------
__device__ __forceinline__ void stage_store(u16* sm, int rr, int q, const float* acc) {
  s16x8 o;
#pragma unroll
  for (int e = 0; e < 8; ++e) o[e] = (short)f2bf(acc[e]);
  int byte = (rr << 8) + (q << 4);
  int swz = byte ^ ((rr & 7) << 4);
  *(s16x8*)((char*)sm + swz) = o;
}

__global__ __launch_bounds__(256) void g_sage(
    const int* rpA, const int* colA, const u16* srcA, const float* scshA, const u16* wtlA,
    const int* rpB, const int* colB, const u16* srcB, const float* scshB, const u16* wtlB,
    const void* root, int root_f32, const float* scshR, const u16* wtr,
    const float* bias, void* out, int out_bf, int N) {
  __shared__ __align__(16) u16 smA[4096];
  __shared__ __align__(16) u16 smB[4096];
  __shared__ __align__(16) u16 smR[4096];
  const int tid = threadIdx.x;
  const int r0 = blockIdx.x * 32;
  const int nbuf = 1 + (rpB ? 1 : 0) + (root ? 1 : 0);

  for (int i = tid; i < nbuf * 512; i += 256) {
    int region = i >> 9;
    int t = i & 511;
    int rr = t >> 4, q = t & 15;
    int row = r0 + rr;
    int c0 = q * 8;
    float acc[8];
#pragma unroll
    for (int e = 0; e < 8; ++e) acc[e] = 0.f;

    bool isRoot = root && (region == nbuf - 1);
    if (isRoot) {
      if (row < N) {
        if (root_f32) {
          const float* rp_ = (const float*)root + (size_t)row * 128 + c0;
          f32x4 lo = *(const f32x4*)rp_;
          f32x4 hi = *(const f32x4*)(rp_ + 4);
          acc[0] = lo.x; acc[1] = lo.y; acc[2] = lo.z; acc[3] = lo.w;
          acc[4] = hi.x; acc[5] = hi.y; acc[6] = hi.z; acc[7] = hi.w;
        } else {
          s16x8 v = *(const s16x8*)((const u16*)root + (size_t)row * 128 + c0);
#pragma unroll
          for (int e = 0; e < 8; ++e) acc[e] = bf2f((u16)v[e]);
        }
        if (scshR) {
#pragma unroll
          for (int e = 0; e < 8; ++e)
            acc[e] = fmaxf(acc[e], 0.f) * scshR[c0 + e] + scshR[128 + c0 + e];
        }
      }
      stage_store(smR, rr, q, acc);
    } else {
      const int* rp = (region == 0) ? rpA : rpB;
      const int* col = (region == 0) ? colA : colB;
      const u16* src = (region == 0) ? srcA : srcB;
      const float* scsh = (region == 0) ? scshA : scshB;
      if (row < N) {
        int j0 = rp[row], j1 = rp[row + 1];
        if (scsh) {
          float sc[8], sh[8];
#pragma unroll
          for (int e = 0; e < 8; ++e) { sc[e] = scsh[c0 + e]; sh[e] = scsh[128 + c0 + e]; }
          for (int j = j0; j < j1; ++j) {
            s16x8 v = *(const s16x8*)(src + (size_t)col[j] * 128 + c0);
#pragma unroll
            for (int e = 0; e < 8; ++e)
              acc[e] += fmaxf(bf2f((u16)v[e]), 0.f) * sc[e] + sh[e];
          }
        } else {
          for (int j = j0; j < j1; ++j) {
            s16x8 v = *(const s16x8*)(src + (size_t)col[j] * 128 + c0);
#pragma unroll
            for (int e = 0; e < 8; ++e) acc[e] += bf2f((u16)v[e]);
          }
        }
        float inv = 1.0f / fmaxf((float)(j1 - j0), 1.0f);
#pragma unroll
        for (int e = 0; e < 8; ++e) acc[e] *= inv;
      }
      stage_store((region == 0) ? smA : smB, rr, q, acc);
    }
  }
  __syncthreads();

  // ---- MFMA: wave wv -> row-tile m=wv>>1, col-tiles nq..nq+3 ----
  const int lane = tid & 63;
  const int wv = tid >> 6;
  const int mi = lane & 15;
  const int kg = lane >> 4;
  const int m = wv >> 1;
  const int nq = (wv & 1) * 4;
  const int arow = m * 16 + mi;
  const int abase = arow << 8;
  const int amask = (arow & 7) << 4;

  f32x4 acc4[4];
#pragma unroll
  for (int t = 0; t < 4; ++t) acc4[t] = (f32x4){0.f, 0.f, 0.f, 0.f};

#pragma unroll
  for (int kt = 0; kt < 4; ++kt) {
    int k0 = kt * 32 + kg * 8;
    int off = (abase + (k0 << 1)) ^ amask;
    s16x8 afA = *(const s16x8*)((const char*)smA + off);
    s16x8 afB, afR;
    if (rpB) afB = *(const s16x8*)((const char*)smB + off);
    if (root) afR = *(const s16x8*)((const char*)smR + off);
#pragma unroll
    for (int t = 0; t < 4; ++t) {
      int cr = (nq + t) * 16 + mi;
      s16x8 b = *(const s16x8*)(wtlA + cr * 128 + k0);
      acc4[t] = __builtin_amdgcn_mfma_f32_16x16x32_bf16(afA, b, acc4[t], 0, 0, 0);
      if (rpB) {
        s16x8 b2 = *(const s16x8*)(wtlB + cr * 128 + k0);
        acc4[t] = __builtin_amdgcn_mfma_f32_16x16x32_bf16(afB, b2, acc4[t], 0, 0, 0);
      }
      if (root) {
        s16x8 b3 = *(const s16x8*)(wtr + cr * 128 + k0);
        acc4[t] = __builtin_amdgcn_mfma_f32_16x16x32_bf16(afR, b3, acc4[t], 0, 0, 0);
      }
    }
  }

  // ---- epilogue: C/D col=lane&15, row=(lane>>4)*4+reg [m89] ----
  int rbase = (lane >> 4) << 2;
#pragma unroll
  for (int t = 0; t < 4; ++t) {
    int c = (nq + t) * 16 + mi;
    float bb = bias[c];
#pragma unroll
    for (int reg = 0; reg < 4; ++reg) {
      int row = r0 + m * 16 + rbase + reg;
      if (row < N) {
        size_t o = (size_t)row * 128 + c;
        float v = acc4[t][reg] + bb;
        if (out_bf) ((u16*)out)[o] = f2bf(v);
        else        ((float*)out)[o] = v;
      }
    }
  }
}

// ---------------- BN stats: 2-stage, NO global atomics ----------------
#define BN_NB 512
// stage 1: block reduces grid-stride portion into LDS, writes 256 partials
__global__ void g_bnstats(const u16* x, long long n4, float* partial) {
  __shared__ float bsum[128];
  __shared__ float bsq[128];
  int tid = threadIdx.x;
  if (tid < 128) { bsum[tid] = 0.f; bsq[tid] = 0.f; }
  __syncthreads();
  long long i0 = (long long)blockIdx.x * 256 + tid;
  long long stride = (long long)gridDim.x * 256;
  int c0 = (int)((i0 << 2) & 127);
  float s0 = 0.f, s1 = 0.f, s2 = 0.f, s3 = 0.f;
  float q0 = 0.f, q1 = 0.f, q2 = 0.f, q3 = 0.f;
  for (long long i = i0; i < n4; i += stride) {
    u64 v = *(const u64*)(x + (i << 2));
    float f0 = fmaxf(bf2f((u16)v), 0.f);
    float f1 = fmaxf(bf2f((u16)(v >> 16)), 0.f);
    float f2 = fmaxf(bf2f((u16)(v >> 32)), 0.f);
    float f3 = fmaxf(bf2f((u16)(v >> 48)), 0.f);
    s0 += f0; s1 += f1; s2 += f2; s3 += f3;
    q0 += f0 * f0; q1 += f1 * f1; q2 += f2 * f2; q3 += f3 * f3;
  }
  atomicAdd(&bsum[c0],     s0); atomicAdd(&bsum[c0 + 1], s1);
  atomicAdd(&bsum[c0 + 2], s2); atomicAdd(&bsum[c0 + 3], s3);
  atomicAdd(&bsq[c0],     q0); atomicAdd(&bsq[c0 + 1], q1);
  atomicAdd(&bsq[c0 + 2], q2); atomicAdd(&bsq[c0 + 3], q3);
  __syncthreads();
  if (tid < 128)      partial[(size_t)blockIdx.x * 256 + tid] = bsum[tid];
  else                partial[(size_t)blockIdx.x * 256 + tid] = bsq[tid - 128];
}

// stage 2: reduce partials, compute scale/shift
__global__ void g_bnfin(const float* partial, const float* g, const float* b,
                        float invN, float* scsh) {
  int c = threadIdx.x;  // 128
  float s = 0.f, q = 0.f;
  for (int blk = 0; blk < BN_NB; ++blk) {
    s += partial[(size_t)blk * 256 + c];
    q += partial[(size_t)blk * 256 + 128 + c];
  }
  float m = s * invN;
  float v = q * invN - m * m;
  float sc = rsqrtf(v + 1e-5f) * g[c];
  scsh[c] = sc;
  scsh[128 + c] = b[c] - m * sc;
}

// ---------------- host ----------------
struct Csr { int* rp; int* col; };

static void build_csr(const int* e, int E, int ndst, Csr c, int* cur, hipStream_t st) {
  HeteroGraphSAGE_52931176955955_kernel<<<nblk7(ndst), 256, 0, st>>>((float*)cur, ndst);
  g_deg<<<nblk7(E), 256, 0, st>>>(e, E, cur);
  g_scan<<<1, 1024, 0, st>>>(cur, c.rp, ndst);
  HeteroGraphSAGE_52931176955955_kernel<<<nblk7(ndst), 256, 0, st>>>((float*)cur, ndst);
  g_fill<<<nblk7(E), 256, 0, st>>>(e, E, c.rp, cur, c.col);
}

static void bn_v7(const u16* h, int n, const float* g, const float* b,
                  float* partial, float* scsh, hipStream_t st) {
  g_bnstats<<<BN_NB, 256, 0, st>>>(h, (long long)n * 32, partial);
  g_bnfin<<<1, 128, 0, st>>>(partial, g, b, 1.0f / (float)n, scsh);
}

extern "C" void kernel_launch(void* const* d_in, const int* in_sizes, int n_in,
                              void* d_out, int out_size, void* d_ws, size_t ws_size,
                              hipStream_t stream) {
  const float* x_paper  = (const float*)d_in[0];
  const float* x_author = (const float*)d_in[1];
  const int* e_pp = (const int*)d_in[3];
  const int* e_pa = (const int*)d_in[4];
  const int* e_ap = (const int*)d_in[5];
  const int* e_ai = (const int*)d_in[6];
  const int* e_ia = (const int*)d_in[7];
  const float* Wl  = (const float*)d_in[8];
  const float* bL  = (const float*)d_in[9];
  const float* Wr  = (const float*)d_in[10];
  const float* bng = (const float*)d_in[11];
  const float* bnb = (const float*)d_in[12];

  const int NP = in_sizes[0] / 128;
  const int NA = in_sizes[1] / 128;
  const int NI = in_sizes[2] / 128;
  const int Epp = in_sizes[3] / 2;
  const int Epa = in_sizes[4] / 2;
  const int Eap = in_sizes[5] / 2;
  const int Eai = in_sizes[6] / 2;
  const int Eia = in_sizes[7] / 2;

  // ws (~154 MB)
  char* ws = (char*)d_ws;
  size_t off = 0;
  u16* xp   = (u16*)(ws + off);   off += (size_t)NP * 256;   // x_paper bf16
  u16* h_p1 = (u16*)(ws + off);   off += (size_t)NP * 256;
  u16* h_a1 = (u16*)(ws + off);   off += (size_t)NA * 256;
  u16* wt   = (u16*)(ws + off);   off += (size_t)25 * 16384 * 2;
  Csr cpp; cpp.rp = (int*)(ws + off); off += (size_t)(NP + 1) * 4;
  Csr cpa; cpa.rp = (int*)(ws + off); off += (size_t)(NA + 1) * 4;
  Csr cap; cap.rp = (int*)(ws + off); off += (size_t)(NP + 1) * 4;
  Csr cai; cai.rp = (int*)(ws + off); off += (size_t)(NI + 1) * 4;
  Csr cia; cia.rp = (int*)(ws + off); off += (size_t)(NA + 1) * 4;
  cpp.col = (int*)(ws + off); off += (size_t)Epp * 4;
  cpa.col = (int*)(ws + off); off += (size_t)Epa * 4;
  cap.col = (int*)(ws + off); off += (size_t)Eap * 4;
  cai.col = (int*)(ws + off); off += (size_t)Eai * 4;
  cia.col = (int*)(ws + off); off += (size_t)Eia * 4;
  int* cur = (int*)(ws + off);       off += (size_t)NP * 4;
  float* partial = (float*)(ws + off); off += (size_t)BN_NB * 256 * 4;
  float* scsh0 = (float*)(ws + off); off += 1024;
  float* scsh1 = (float*)(ws + off); off += 1024;
  float* scsh2 = (float*)(ws + off); off += 1024;
  float* scsh3 = (float*)(ws + off); off += 1024;
  float* scsh4 = (float*)(ws + off); off += 1024;
  float* cb    = (float*)(ws + off); off += 3 * 512;

  // d_out fp32 regions: p2 | a2 | i2; raw bf16 hiddens parked inside
  float* outp = (float*)d_out;
  float* outa = outp + (size_t)NP * 128;
  float* outi = outa + (size_t)NA * 128;
  u16* h_p0 = (u16*)outp;                         // first half of p-region
  u16* h_a0 = (u16*)outa;                         // first half of a-region
  u16* h_i1 = (u16*)outp + (size_t)NP * 128;      // second half of p-region

  g_wprep<<<nblk7(25 * 16384), 256, 0, stream>>>(Wl, Wr, wt, 25 * 16384);
  g_bprep<<<1, 128, 0, stream>>>(bL, cb);
  g_cvt<<<nblk7((long long)NP * 32), 256, 0, stream>>>(x_paper, xp, (long long)NP * 32);
  build_csr(e_pp, Epp, NP, cpp, cur, stream);
  build_csr(e_pa, Epa, NA, cpa, cur, stream);
  build_csr(e_ap, Eap, NP, cap, cur, stream);
  build_csr(e_ai, Eai, NI, cai, cur, stream);
  build_csr(e_ia, Eia, NA, cia, cur, stream);

  const float* nof = (const float*)0;
  const int* noi = (const int*)0;
  const u16* nou = (const u16*)0;

#define WT(i) (wt + (size_t)(i) * 16384)

  // ---- Layer 0 (raw outputs; BN stats -> scsh) ----
  g_sage<<<(NP + 31) / 32, 256, 0, stream>>>(
      cpp.rp, cpp.col, xp, nof, WT(0), noi, noi, nou, nof, nou,
      xp, 0, nof, WT(11), bL + 0 * 128, h_p0, 1, NP);
  bn_v7(h_p0, NP, bng + 0 * 128, bnb + 0 * 128, partial, scsh0, stream);
  g_sage<<<(NA + 31) / 32, 256, 0, stream>>>(
      cpa.rp, cpa.col, xp, nof, WT(1), noi, noi, nou, nof, nou,
      x_author, 1, nof, WT(12), bL + 1 * 128, h_a0, 1, NA);
  bn_v7(h_a0, NA, bng + 1 * 128, bnb + 1 * 128, partial, scsh1, stream);

  // ---- Layer 1 ----
  g_sage<<<(NP + 31) / 32, 256, 0, stream>>>(             // p1 = pp + ap (dual)
      cpp.rp, cpp.col, h_p0, scsh0, WT(2), cap.rp, cap.col, h_a0, scsh1, WT(4),
      h_p0, 0, scsh0, WT(22), cb, h_p1, 1, NP);
  bn_v7(h_p1, NP, bng + 2 * 128, bnb + 2 * 128, partial, scsh2, stream);
  g_sage<<<(NA + 31) / 32, 256, 0, stream>>>(             // a1 = pa
      cpa.rp, cpa.col, h_p0, scsh0, WT(3), noi, noi, nou, nof, nou,
      h_a0, 0, scsh1, WT(14), bL + 3 * 128, h_a1, 1, NA);
  bn_v7(h_a1, NA, bng + 3 * 128, bnb + 3 * 128, partial, scsh3, stream);
  g_sage<<<(NI + 31) / 32, 256, 0, stream>>>(             // i1 = ai (no root)
      cai.rp, cai.col, h_a0, scsh1, WT(5), noi, noi, nou, nof, nou,
      (const void*)0, 0, nof, nou, bL + 5 * 128, h_i1, 1, NI);
  bn_v7(h_i1, NI, bng + 4 * 128, bnb + 4 * 128, partial, scsh4, stream);

  // ---- Layer 2 (order: a2, i2, then p2 — p2 clobbers h_i1's region) ----
  g_sage<<<(NA + 31) / 32, 256, 0, stream>>>(             // a2 = pa + ia (dual)
      cpa.rp, cpa.col, h_p1, scsh2, WT(7), cia.rp, cia.col, h_i1, scsh4, WT(10),
      h_a1, 0, scsh3, WT(24), cb + 256, outa, 0, NA);
  g_sage<<<(NI + 31) / 32, 256, 0, stream>>>(             // i2 = ai
      cai.rp, cai.col, h_a1, scsh3, WT(9), noi, noi, nou, nof, nou,
      h_i1, 0, scsh4, WT(20), bL + 9 * 128, outi, 0, NI);
  g_sage<<<(NP + 31) / 32, 256, 0, stream>>>(             // p2 = pp + ap (dual)
      cpp.rp, cpp.col, h_p1, scsh2, WT(6), cap.rp, cap.col, h_a1, scsh3, WT(8),
      h_p1, 0, scsh2, WT(23), cb + 128, outp, 0, NP);

#undef WT
  (void)n_in; (void)ws_size; (void)out_size;
}